// Round 13
// baseline (321.465 us; speedup 1.0000x reference)
//
#include <hip/hip_runtime.h>
#include <hip/hip_bf16.h>

typedef unsigned short u16;
typedef unsigned int   u32;
typedef __attribute__((ext_vector_type(8))) short bf16x8;
typedef __attribute__((ext_vector_type(4))) float f32x4;

static constexpr int kS = 128, kD = 1024, kC = 65536, kN = 512, kNNZ = 262144;

__device__ __forceinline__ u16 f2bf(float x) {
  u32 u = __float_as_uint(x);
  u32 r = (u + 0x7fffu + ((u >> 16) & 1u)) >> 16;   // RTNE
  return (u16)r;
}
__device__ __forceinline__ u32 pack2(float a, float b) {
  return (u32)f2bf(a) | ((u32)f2bf(b) << 16);
}
// HW packed convert: v_cvt_pk_bf16_f32 (RTNE)
__device__ __forceinline__ u32 pk(float a, float b) {
  __hip_bfloat162 h = __float22bfloat162_rn(float2{a, b});
  union { __hip_bfloat162 v; u32 u; } c; c.v = h;
  return c.u;
}
__device__ __forceinline__ float bf_lo(u32 v) { return __uint_as_float(v << 16); }
__device__ __forceinline__ float bf_hi(u32 v) { return __uint_as_float(v & 0xffff0000u); }

__device__ __forceinline__ void gload16(const void* g, void* l) {
  __builtin_amdgcn_global_load_lds(
      (const __attribute__((address_space(1))) void*)g,
      (__attribute__((address_space(3))) void*)l, 16, 0, 0);
}

// ---------------- BN stats: two-stage partial sums ----------------
__global__ void k_bn_part(const float* __restrict__ enc, const int* __restrict__ bidx,
                          const int* __restrict__ tgt, float* __restrict__ part) {
  __shared__ int offs[64];
  int n0 = blockIdx.y * 64;
  if (threadIdx.x < 64) offs[threadIdx.x] = bidx[n0 + threadIdx.x] * kS + tgt[n0 + threadIdx.x];
  __syncthreads();
  int d = blockIdx.x * 256 + threadIdx.x;
  float s = 0.f, ss = 0.f;
  for (int i = 0; i < 64; ++i) {
    float v = enc[(size_t)offs[i] * kD + d];
    s += v; ss += v * v;
  }
  part[(blockIdx.y * 2 + 0) * kD + d] = s;
  part[(blockIdx.y * 2 + 1) * kD + d] = ss;
}

__global__ void k_bn_fin(const float* __restrict__ part, float* __restrict__ mean,
                         float* __restrict__ rstd) {
  int d = blockIdx.x * 256 + threadIdx.x;
  float s = 0.f, ss = 0.f;
#pragma unroll
  for (int b = 0; b < 8; ++b) {
    s  += part[(b * 2 + 0) * kD + d];
    ss += part[(b * 2 + 1) * kD + d];
  }
  float m = s * (1.f / kN);
  float var = ss * (1.f / kN) - m * m;
  mean[d] = m;
  rstd[d] = 1.f / sqrtf(var + 1e-5f);
}

// ---------------- BN apply + pack into fragment-major Bp ----------------
// Bp entry (g, n) at flat g*512+n, 8 bf16 = h0[n][g*8 .. g*8+8]
__global__ void k_bn_pack(const float* __restrict__ enc, const int* __restrict__ bidx,
                          const int* __restrict__ tgt, const float* __restrict__ mean,
                          const float* __restrict__ rstd, u16* __restrict__ Bp) {
  int i = blockIdx.x * 256 + threadIdx.x;     // 256 blocks x 256 = 65536 entries
  int n = i & 511;
  int g = i >> 9;
  int k0 = g * 8;
  size_t src = (size_t)(bidx[n] * kS + tgt[n]) * kD + k0;
  float4 v0 = *(const float4*)(enc + src);
  float4 v1 = *(const float4*)(enc + src + 4);
  float4 m0 = *(const float4*)(mean + k0);
  float4 m1 = *(const float4*)(mean + k0 + 4);
  float4 r0 = *(const float4*)(rstd + k0);
  float4 r1 = *(const float4*)(rstd + k0 + 4);
  u32 q0 = pack2((v0.x - m0.x) * r0.x, (v0.y - m0.y) * r0.y);
  u32 q1 = pack2((v0.z - m0.z) * r0.z, (v0.w - m0.w) * r0.w);
  u32 q2 = pack2((v1.x - m1.x) * r1.x, (v1.y - m1.y) * r1.y);
  u32 q3 = pack2((v1.z - m1.z) * r1.z, (v1.w - m1.w) * r1.w);
  *(uint4*)(Bp + (size_t)i * 8) = make_uint4(q0, q1, q2, q3);
}

// ---------------- sort: histogram / scan / scatter ----------------
__global__ void k_hist(const int* __restrict__ rows, int* __restrict__ hist) {
  int e = blockIdx.x * blockDim.x + threadIdx.x;
  if (e < kNNZ) atomicAdd(&hist[rows[e]], 1);
}

__global__ __launch_bounds__(1024) void k_scan(int* __restrict__ hist, int* __restrict__ cursor) {
  __shared__ int sm[1024];
  int t = threadIdx.x;
  int base = t * 64;
  int sum = 0;
  for (int i = 0; i < 64; ++i) sum += hist[base + i];
  sm[t] = sum;
  __syncthreads();
  for (int off = 1; off < 1024; off <<= 1) {
    int v = (t >= off) ? sm[t - off] : 0;
    __syncthreads();
    sm[t] += v;
    __syncthreads();
  }
  int run = sm[t] - sum;
  for (int i = 0; i < 64; ++i) {
    int v = hist[base + i];
    hist[base + i] = run;
    cursor[base + i] = run;
    run += v;
  }
  if (t == 1023) hist[kC] = run;
}

__global__ void k_scatter(const int* __restrict__ rows, const int* __restrict__ cols,
                          const float* __restrict__ vals, int* __restrict__ cursor,
                          int* __restrict__ scol, float* __restrict__ sval) {
  int e = blockIdx.x * blockDim.x + threadIdx.x;
  if (e < kNNZ) {
    int r = rows[e];
    int p = atomicAdd(&cursor[r], 1);
    scol[p] = cols[e];
    sval[p] = vals[e];
  }
}

// ---------------- fused GEMM v8: 2-phase super-steps, issue-after-barrier / drain-after-full-super ----------
// BM=128 x BN=512 (W once), BK=32, 1024 thr (16 waves = 2m x 8n), acc[4][4], 1 block/CU.
// LDS 160 KB: B 2 super-bufs x 2 phases x 32 KB (DMA from fragment-major Bp, linear) +
//             A 2 super-bufs x 2 phases x 8 KB (reg-staged f32 -> cvt_pk -> swizzled ds_write).
// Super s: barrier -> issue B-DMA(s+1) + A-load ph0(s+1) -> MFMA ph0 -> write A ph0(s+1),
//          load A ph1(s+1) -> MFMA ph1 -> write A ph1(s+1) -> barrier.
// Every load is in flight for ~a full super (>3000 cyc >> HBM 900) before its drain.
__global__ __launch_bounds__(1024, 1)
void k_gemm_f8(const float* __restrict__ W, const u16* __restrict__ Bp,
               const float* __restrict__ bias, u16* __restrict__ h1t) {
  __shared__ __align__(16) u16 lds[81920];   // 163840 B = full 160 KB pool
  u16* Bb = lds;                              // [buf][phase][2048 slots][8 u16]
  u16* Ab = lds + 65536;                      // [buf][phase][128 r][32 k] (swizzled chunks)
  const int t = threadIdx.x;
  const int l = t & 63, w = t >> 6;           // 16 waves
  const int wm = w >> 3, wn = (w & 7) * 64;   // 2m x 8n
  const int cb = blockIdx.x * 128;
  const int q = l >> 4, ln = l & 15;

  // A staging map: thread -> row ar (128), f32x4 slot as (8/row); swizzle chunk^(row&3)
  const int ar = t >> 3, as = t & 7;
  const float* gA = W + (size_t)(cb + ar) * kD + as * 4;
  const int awoff = ar * 32 + (((as >> 1) ^ (ar & 3)) * 8) + (as & 1) * 4;

  f32x4 acc[4][4];
#pragma unroll
  for (int a = 0; a < 4; ++a)
#pragma unroll
    for (int b = 0; b < 4; ++b) acc[a][b] = (f32x4){0.f, 0.f, 0.f, 0.f};

  // ---- prologue: stage super 0 (phases 0,1) into buf 0 ----
  {
    float4 a0 = *(const float4*)(gA);
    float4 a1 = *(const float4*)(gA + 32);
    gload16(Bp + (size_t)t * 8,               (char*)Bb + t * 16);
    gload16(Bp + (size_t)(t + 1024) * 8,      (char*)Bb + (t + 1024) * 16);
    gload16(Bp + (size_t)(2048 + t) * 8,      (char*)Bb + 32768 + t * 16);
    gload16(Bp + (size_t)(2048 + t + 1024) * 8, (char*)Bb + 32768 + (t + 1024) * 16);
    *(uint2*)(Ab + awoff)        = make_uint2(pk(a0.x, a0.y), pk(a0.z, a0.w));
    *(uint2*)(Ab + 4096 + awoff) = make_uint2(pk(a1.x, a1.y), pk(a1.z, a1.w));
  }
  __syncthreads();

#pragma unroll 2
  for (int ss = 0; ss < 16; ++ss) {
    const int cu = ss & 1, nx = cu ^ 1;
    const u16* Bc = Bb + cu * 32768 / 2;      // careful: u16 units -> 32 KB = 16384 u16
    const u16* Ac = Ab + cu * 8192 / 2;       // 8 KB*2phases = 8192 u16 per buf
    // NOTE: offsets in u16 units: B super-buf = 32768 B *2phases... see layout below
    // B layout (u16): buf*32768? -> per buf: 2 phases x 16384 u16 = 32768 u16 (64 KB) ✓
    const u16* Bc0 = Bb + cu * 32768;         // phase0 of current super
    const u16* Bc1 = Bc0 + 16384;             // phase1
    const u16* Ac0 = Ab + cu * 8192;          // phase0 (4096 u16 = 8 KB)
    const u16* Ac1 = Ac0 + 4096;
    (void)Bc; (void)Ac;

    float4 nA0, nA1;
    // ---- issue next super's loads right after the barrier ----
    if (ss < 15) {
      const int ph = (ss + 1) * 2;
      nA0 = *(const float4*)(gA + ph * 32);
      char* Bn = (char*)(Bb + nx * 32768);
      gload16(Bp + ((size_t)ph * 2048 + t) * 8,              Bn + t * 16);
      gload16(Bp + ((size_t)ph * 2048 + t + 1024) * 8,       Bn + (t + 1024) * 16);
      gload16(Bp + ((size_t)(ph + 1) * 2048 + t) * 8,        Bn + 32768 + t * 16);
      gload16(Bp + ((size_t)(ph + 1) * 2048 + t + 1024) * 8, Bn + 32768 + (t + 1024) * 16);
    }
    // ---- phase 0 ----
    __builtin_amdgcn_s_setprio(1);
    {
      bf16x8 bv[4], af[4];
#pragma unroll
      for (int nb = 0; nb < 4; ++nb)
        bv[nb] = *(const bf16x8*)(Bc0 + (q * 512 + wn + nb * 16 + ln) * 8);
#pragma unroll
      for (int mb = 0; mb < 4; ++mb) {
        int rr = wm * 64 + mb * 16 + ln;
        af[mb] = *(const bf16x8*)(Ac0 + rr * 32 + ((q ^ (rr & 3)) * 8));
      }
#pragma unroll
      for (int mb = 0; mb < 4; ++mb)
#pragma unroll
        for (int nb = 0; nb < 4; ++nb)
          acc[mb][nb] = __builtin_amdgcn_mfma_f32_16x16x32_bf16(af[mb], bv[nb], acc[mb][nb], 0, 0, 0);
    }
    __builtin_amdgcn_s_setprio(0);
    // write-late A phase0(next), then issue A phase1(next) load
    if (ss < 15) {
      *(uint2*)(Ab + nx * 8192 + awoff) = make_uint2(pk(nA0.x, nA0.y), pk(nA0.z, nA0.w));
      nA1 = *(const float4*)(gA + ((ss + 1) * 2 + 1) * 32);
    }
    // ---- phase 1 ----
    __builtin_amdgcn_s_setprio(1);
    {
      bf16x8 bv[4], af[4];
#pragma unroll
      for (int nb = 0; nb < 4; ++nb)
        bv[nb] = *(const bf16x8*)(Bc1 + (q * 512 + wn + nb * 16 + ln) * 8);
#pragma unroll
      for (int mb = 0; mb < 4; ++mb) {
        int rr = wm * 64 + mb * 16 + ln;
        af[mb] = *(const bf16x8*)(Ac1 + rr * 32 + ((q ^ (rr & 3)) * 8));
      }
#pragma unroll
      for (int mb = 0; mb < 4; ++mb)
#pragma unroll
        for (int nb = 0; nb < 4; ++nb)
          acc[mb][nb] = __builtin_amdgcn_mfma_f32_16x16x32_bf16(af[mb], bv[nb], acc[mb][nb], 0, 0, 0);
    }
    __builtin_amdgcn_s_setprio(0);
    if (ss < 15) {
      *(uint2*)(Ab + nx * 8192 + 4096 + awoff) = make_uint2(pk(nA1.x, nA1.y), pk(nA1.z, nA1.w));
    }
    __syncthreads();   // drains: B-DMA(ss+1) issued a full super ago (~free) + tiny lgkm
  }

  // epilogue: + bias, swish, bf16 store (C/D map: col=lane&15, row=(lane>>4)*4+i)
#pragma unroll
  for (int mb = 0; mb < 4; ++mb) {
    int rb = wm * 64 + mb * 16 + q * 4;
#pragma unroll
    for (int i = 0; i < 4; ++i) {
      int c = cb + rb + i;
      float bvs = bias[c];
#pragma unroll
      for (int nb = 0; nb < 4; ++nb) {
        float x = acc[mb][nb][i] + bvs;
        float sw = x / (1.f + __expf(-x));
        h1t[(size_t)c * kN + (wn + nb * 16 + ln)] = f2bf(sw);
      }
    }
  }
}

// ---------------- spmm: 32 rows/block, 2-deep edge pipeline, transposed write ----------------
#define FMA8(cv, v)                                                        \
  a0 = fmaf(v, bf_lo(cv.x), a0); a1 = fmaf(v, bf_hi(cv.x), a1);            \
  a2 = fmaf(v, bf_lo(cv.y), a2); a3 = fmaf(v, bf_hi(cv.y), a3);            \
  a4 = fmaf(v, bf_lo(cv.z), a4); a5 = fmaf(v, bf_hi(cv.z), a5);            \
  a6 = fmaf(v, bf_lo(cv.w), a6); a7 = fmaf(v, bf_hi(cv.w), a7);

__global__ __launch_bounds__(512)
void k_spmm(const u16* __restrict__ h1t, const int* __restrict__ rowptr,
            const int* __restrict__ scol, const float* __restrict__ sval,
            float* __restrict__ out) {
  __shared__ float tile[32 * 512];   // XOR-swizzled, 64 KB
  int r0 = blockIdx.x * 32;
  int t = threadIdx.x, w = t >> 6, l = t & 63;
#pragma unroll
  for (int j = 0; j < 4; ++j) {
    int rl = w * 4 + j;
    int r = r0 + rl;
    uint4 hv = ((const uint4*)(h1t + (size_t)r * kN))[l];
    float a0 = bf_lo(hv.x), a1 = bf_hi(hv.x), a2 = bf_lo(hv.y), a3 = bf_hi(hv.y);
    float a4 = bf_lo(hv.z), a5 = bf_hi(hv.z), a6 = bf_lo(hv.w), a7 = bf_hi(hv.w);
    int e0 = rowptr[r], e1 = rowptr[r + 1];
    uint4 cv0 = {}, cv1 = {};
    float v0 = 0.f, v1 = 0.f;
    if (e0 < e1) {                    // 2-deep pipeline: two independent gather regs
      v0 = sval[e0];
      cv0 = ((const uint4*)(h1t + (size_t)scol[e0] * kN))[l];
    }
    if (e0 + 1 < e1) {
      v1 = sval[e0 + 1];
      cv1 = ((const uint4*)(h1t + (size_t)scol[e0 + 1] * kN))[l];
    }
    for (int e = e0; e < e1; e += 2) {
      FMA8(cv0, v0);
      if (e + 2 < e1) {
        v0 = sval[e + 2];
        cv0 = ((const uint4*)(h1t + (size_t)scol[e + 2] * kN))[l];
      }
      if (e + 1 < e1) {
        FMA8(cv1, v1);
        if (e + 3 < e1) {
          v1 = sval[e + 3];
          cv1 = ((const uint4*)(h1t + (size_t)scol[e + 3] * kN))[l];
        }
      }
    }
    int sw = (rl & 7) << 2;          // XOR bits 2..4 keep float4 groups intact
    *(float4*)&tile[rl * 512 + ((8 * l) ^ sw)]     = make_float4(a0, a1, a2, a3);
    *(float4*)&tile[rl * 512 + ((8 * l + 4) ^ sw)] = make_float4(a4, a5, a6, a7);
  }
  __syncthreads();
  int r = l & 31;
  int swr = (r & 7) << 2;
#pragma unroll
  for (int it = 0; it < 32; ++it) {
    int n = it * 16 + w * 2 + (l >> 5);
    out[(size_t)n * kC + r0 + r] = tile[r * 512 + (n ^ swr)];
  }
}

extern "C" void kernel_launch(void* const* d_in, const int* in_sizes, int n_in,
                              void* d_out, int out_size, void* d_ws, size_t ws_size,
                              hipStream_t stream) {
  (void)in_sizes; (void)n_in; (void)out_size; (void)ws_size;
  const float* enc   = (const float*)d_in[0];
  const float* W     = (const float*)d_in[1];
  const float* bias  = (const float*)d_in[2];
  const float* Avals = (const float*)d_in[3];
  const int*   bidx  = (const int*)d_in[4];
  const int*   tgt   = (const int*)d_in[5];
  const int*   Arow  = (const int*)d_in[6];
  const int*   Acol  = Arow + kNNZ;
  float* out = (float*)d_out;

  char* ws = (char*)d_ws;
  float* mean   = (float*)(ws);                       //   4 KB
  float* rstd   = (float*)(ws + 4096);                //   4 KB
  u16*   Bp     = (u16*)  (ws + 8192);                //   1 MB fragment-major h0
  int*   rowptr = (int*)  (ws + 1056768);             // 256 KB (+1)
  int*   cursor = (int*)  (ws + 1319168);             // 256 KB
  int*   scol   = (int*)  (ws + 1581312);             //   1 MB
  float* sval   = (float*)(ws + 2629888);             //   1 MB
  float* part   = (float*)(ws + 3678464);             //  64 KB
  u16*   h1t    = (u16*)  (ws + 4194304);             //  64 MB

  hipMemsetAsync(rowptr, 0, (kC + 1) * sizeof(int), stream);
  k_bn_part<<<dim3(4, 8), 256, 0, stream>>>(enc, bidx, tgt, part);
  k_bn_fin<<<4, 256, 0, stream>>>(part, mean, rstd);
  k_bn_pack<<<256, 256, 0, stream>>>(enc, bidx, tgt, mean, rstd, Bp);
  k_hist<<<kNNZ / 256, 256, 0, stream>>>(Arow, rowptr);
  k_scan<<<1, 1024, 0, stream>>>(rowptr, cursor);
  k_scatter<<<kNNZ / 256, 256, 0, stream>>>(Arow, Acol, Avals, cursor, scol, sval);
  k_gemm_f8<<<kC / 128, 1024, 0, stream>>>(W, Bp, bias, h1t);
  k_spmm<<<kC / 32, 512, 0, stream>>>(h1t, rowptr, scol, sval, out);
}

// Round 16
// 289.051 us; speedup vs baseline: 1.1121x; 1.1121x over previous
//
#include <hip/hip_runtime.h>
#include <hip/hip_bf16.h>

typedef unsigned short u16;
typedef unsigned int   u32;
typedef __attribute__((ext_vector_type(8))) short bf16x8;
typedef __attribute__((ext_vector_type(4))) float f32x4;

static constexpr int kS = 128, kD = 1024, kC = 65536, kN = 512, kNNZ = 262144;

__device__ __forceinline__ u16 f2bf(float x) {
  u32 u = __float_as_uint(x);
  u32 r = (u + 0x7fffu + ((u >> 16) & 1u)) >> 16;   // RTNE
  return (u16)r;
}
__device__ __forceinline__ u32 pack2(float a, float b) {
  return (u32)f2bf(a) | ((u32)f2bf(b) << 16);
}
// HW packed convert: v_cvt_pk_bf16_f32 (RTNE), a -> low16, b -> high16
__device__ __forceinline__ u32 pk(float a, float b) {
  __hip_bfloat162 h = __float22bfloat162_rn(float2{a, b});
  union { __hip_bfloat162 v; u32 u; } c; c.v = h;
  return c.u;
}
__device__ __forceinline__ float bf_lo(u32 v) { return __uint_as_float(v << 16); }
__device__ __forceinline__ float bf_hi(u32 v) { return __uint_as_float(v & 0xffff0000u); }

// ---------------- BN stats: two-stage partial sums ----------------
__global__ void k_bn_part(const float* __restrict__ enc, const int* __restrict__ bidx,
                          const int* __restrict__ tgt, float* __restrict__ part) {
  __shared__ int offs[64];
  int n0 = blockIdx.y * 64;
  if (threadIdx.x < 64) offs[threadIdx.x] = bidx[n0 + threadIdx.x] * kS + tgt[n0 + threadIdx.x];
  __syncthreads();
  int d = blockIdx.x * 256 + threadIdx.x;
  float s = 0.f, ss = 0.f;
  for (int i = 0; i < 64; ++i) {
    float v = enc[(size_t)offs[i] * kD + d];
    s += v; ss += v * v;
  }
  part[(blockIdx.y * 2 + 0) * kD + d] = s;
  part[(blockIdx.y * 2 + 1) * kD + d] = ss;
}

__global__ void k_bn_fin(const float* __restrict__ part, float* __restrict__ mean,
                         float* __restrict__ rstd) {
  int d = blockIdx.x * 256 + threadIdx.x;
  float s = 0.f, ss = 0.f;
#pragma unroll
  for (int b = 0; b < 8; ++b) {
    s  += part[(b * 2 + 0) * kD + d];
    ss += part[(b * 2 + 1) * kD + d];
  }
  float m = s * (1.f / kN);
  float var = ss * (1.f / kN) - m * m;
  mean[d] = m;
  rstd[d] = 1.f / sqrtf(var + 1e-5f);
}

// ---------------- BN apply + pack into fragment-major Bp ----------------
// Bp entry (g, n) at flat g*512+n, 8 bf16 = h0[n][g*8 .. g*8+8]
__global__ void k_bn_pack(const float* __restrict__ enc, const int* __restrict__ bidx,
                          const int* __restrict__ tgt, const float* __restrict__ mean,
                          const float* __restrict__ rstd, u16* __restrict__ Bp) {
  int i = blockIdx.x * 256 + threadIdx.x;     // 256 blocks x 256 = 65536 entries
  int n = i & 511;
  int g = i >> 9;
  int k0 = g * 8;
  size_t src = (size_t)(bidx[n] * kS + tgt[n]) * kD + k0;
  float4 v0 = *(const float4*)(enc + src);
  float4 v1 = *(const float4*)(enc + src + 4);
  float4 m0 = *(const float4*)(mean + k0);
  float4 m1 = *(const float4*)(mean + k0 + 4);
  float4 r0 = *(const float4*)(rstd + k0);
  float4 r1 = *(const float4*)(rstd + k0 + 4);
  u32 q0 = pack2((v0.x - m0.x) * r0.x, (v0.y - m0.y) * r0.y);
  u32 q1 = pack2((v0.z - m0.z) * r0.z, (v0.w - m0.w) * r0.w);
  u32 q2 = pack2((v1.x - m1.x) * r1.x, (v1.y - m1.y) * r1.y);
  u32 q3 = pack2((v1.z - m1.z) * r1.z, (v1.w - m1.w) * r1.w);
  *(uint4*)(Bp + (size_t)i * 8) = make_uint4(q0, q1, q2, q3);
}

// ---------------- sort: histogram / scan / scatter ----------------
__global__ void k_hist(const int* __restrict__ rows, int* __restrict__ hist) {
  int e = blockIdx.x * blockDim.x + threadIdx.x;
  if (e < kNNZ) atomicAdd(&hist[rows[e]], 1);
}

__global__ __launch_bounds__(1024) void k_scan(int* __restrict__ hist, int* __restrict__ cursor) {
  __shared__ int sm[1024];
  int t = threadIdx.x;
  int base = t * 64;
  int sum = 0;
  for (int i = 0; i < 64; ++i) sum += hist[base + i];
  sm[t] = sum;
  __syncthreads();
  for (int off = 1; off < 1024; off <<= 1) {
    int v = (t >= off) ? sm[t - off] : 0;
    __syncthreads();
    sm[t] += v;
    __syncthreads();
  }
  int run = sm[t] - sum;
  for (int i = 0; i < 64; ++i) {
    int v = hist[base + i];
    hist[base + i] = run;
    cursor[base + i] = run;
    run += v;
  }
  if (t == 1023) hist[kC] = run;
}

__global__ void k_scatter(const int* __restrict__ rows, const int* __restrict__ cols,
                          const float* __restrict__ vals, int* __restrict__ cursor,
                          int* __restrict__ scol, float* __restrict__ sval) {
  int e = blockIdx.x * blockDim.x + threadIdx.x;
  if (e < kNNZ) {
    int r = rows[e];
    int p = atomicAdd(&cursor[r], 1);
    scol[p] = cols[e];
    sval[p] = vals[e];
  }
}

// ---------------- fused GEMM v5 (R10, known-good): reg-stage A + HW cvt_pk, bf16 XOR-swizzled LDS ----------------
// BM=64 x BN=512, BK=64, 512 thr (8 waves, 1M x 8N), acc[4][4], 2 blocks/CU.
__global__ __launch_bounds__(512, 4)
void k_gemm_f5(const float* __restrict__ W, const u16* __restrict__ Bp,
               const float* __restrict__ bias, u16* __restrict__ h1t) {
  __shared__ __align__(16) u16 Ab[2 * 64 * 64];   // 2 x 8 KB
  const int t = threadIdx.x;
  const int l = t & 63, w = t >> 6;
  const int wn = w * 64;
  const int cb = blockIdx.x * 64;
  const int q = l >> 4, ln = l & 15;

  // staging map: thread t -> row sr = t>>3, chunk sc = t&7 (8 consecutive f32 = 32 B)
  const int sr = t >> 3, sc = t & 7;
  const float* gA = W + (size_t)(cb + sr) * kD + sc * 8;
  const int swoff = sr * 64 + ((sc ^ (sr & 7)) * 8);   // u16 units within one buffer

  // B fragment base: frag (g, n) at Bp[(g*512+n)*8]; g = tt*8 + ks*4 + q
  const u16* gB = Bp + (size_t)q * 4096 + (size_t)(wn + ln) * 8;

  f32x4 acc[4][4];
#pragma unroll
  for (int a = 0; a < 4; ++a)
#pragma unroll
    for (int b = 0; b < 4; ++b) acc[a][b] = (f32x4){0.f, 0.f, 0.f, 0.f};

  // prologue: stage tile 0 into buffer 0
  {
    float4 a0 = *(const float4*)(gA);
    float4 a1 = *(const float4*)(gA + 4);
    *(uint4*)(Ab + swoff) =
        make_uint4(pk(a0.x, a0.y), pk(a0.z, a0.w), pk(a1.x, a1.y), pk(a1.z, a1.w));
  }
  __syncthreads();

#pragma unroll 2
  for (int tt = 0; tt < 16; ++tt) {
    const int cur = tt & 1;
    // issue next tile's global loads first (in flight across the MFMA phase)
    float4 na0, na1;
    if (tt < 15) {
      na0 = *(const float4*)(gA + (tt + 1) * 64);
      na1 = *(const float4*)(gA + (tt + 1) * 64 + 4);
    }
    const u16* curb = Ab + cur * 4096;
#pragma unroll
    for (int ks = 0; ks < 2; ++ks) {
      bf16x8 bv[4];
#pragma unroll
      for (int nb = 0; nb < 4; ++nb)
        bv[nb] = *(const bf16x8*)(gB + (size_t)((tt * 8 + ks * 4) * 4096) + nb * 128);
#pragma unroll
      for (int mb = 0; mb < 4; ++mb) {
        int rr = mb * 16 + ln;
        bf16x8 af = *(const bf16x8*)(curb + rr * 64 + (((ks * 4 + q) ^ (rr & 7)) * 8));
#pragma unroll
        for (int nb = 0; nb < 4; ++nb)
          acc[mb][nb] = __builtin_amdgcn_mfma_f32_16x16x32_bf16(af, bv[nb], acc[mb][nb], 0, 0, 0);
      }
    }
    // stage next tile into the other buffer (safe: prev reads of it drained at last barrier)
    if (tt < 15) {
      *(uint4*)(Ab + (cur ^ 1) * 4096 + swoff) =
          make_uint4(pk(na0.x, na0.y), pk(na0.z, na0.w), pk(na1.x, na1.y), pk(na1.z, na1.w));
    }
    __syncthreads();
  }

  // epilogue: + bias, swish, bf16 store (C/D map: col=lane&15, row=(lane>>4)*4+i)
#pragma unroll
  for (int mb = 0; mb < 4; ++mb) {
    int rb = mb * 16 + q * 4;
#pragma unroll
    for (int i = 0; i < 4; ++i) {
      int c = cb + rb + i;
      float bvs = bias[c];
#pragma unroll
      for (int nb = 0; nb < 4; ++nb) {
        float x = acc[mb][nb][i] + bvs;
        float sw = x / (1.f + __expf(-x));
        h1t[(size_t)c * kN + (wn + nb * 16 + ln)] = f2bf(sw);
      }
    }
  }
}

// ---------------- spmm v2: 4-row x 2-deep interleaved gather pipeline ----------------
#define FMA8A(aj, cv, v)                                                       \
  aj[0] = fmaf(v, bf_lo(cv.x), aj[0]); aj[1] = fmaf(v, bf_hi(cv.x), aj[1]);    \
  aj[2] = fmaf(v, bf_lo(cv.y), aj[2]); aj[3] = fmaf(v, bf_hi(cv.y), aj[3]);    \
  aj[4] = fmaf(v, bf_lo(cv.z), aj[4]); aj[5] = fmaf(v, bf_hi(cv.z), aj[5]);    \
  aj[6] = fmaf(v, bf_lo(cv.w), aj[6]); aj[7] = fmaf(v, bf_hi(cv.w), aj[7]);

__global__ __launch_bounds__(512)
void k_spmm(const u16* __restrict__ h1t, const int* __restrict__ rowptr,
            const int* __restrict__ scol, const float* __restrict__ sval,
            float* __restrict__ out) {
  __shared__ float tile[32 * 512];   // XOR-swizzled, 64 KB
  int r0 = blockIdx.x * 32;
  int t = threadIdx.x, w = t >> 6, l = t & 63;

  float a[4][8];
  int e[4], e1[4];
  uint4 cvA[4], cvB[4];
  float vA[4], vB[4];

  // residual init + row ranges (wave-uniform per j)
#pragma unroll
  for (int j = 0; j < 4; ++j) {
    int r = r0 + w * 4 + j;
    uint4 hv = ((const uint4*)(h1t + (size_t)r * kN))[l];
    a[j][0] = bf_lo(hv.x); a[j][1] = bf_hi(hv.x);
    a[j][2] = bf_lo(hv.y); a[j][3] = bf_hi(hv.y);
    a[j][4] = bf_lo(hv.z); a[j][5] = bf_hi(hv.z);
    a[j][6] = bf_lo(hv.w); a[j][7] = bf_hi(hv.w);
    e[j] = rowptr[r];
    e1[j] = rowptr[r + 1];
  }
  // prologue: 2-deep fill (8 independent gathers in flight per wave)
#pragma unroll
  for (int j = 0; j < 4; ++j) {
    bool ha = e[j] < e1[j];
    int  c0 = ha ? scol[e[j]] : 0;
    vA[j]   = ha ? sval[e[j]] : 0.f;
    cvA[j] = ((const uint4*)(h1t + (size_t)c0 * kN))[l];
    bool hb = e[j] + 1 < e1[j];
    int  c1 = hb ? scol[e[j] + 1] : 0;
    vB[j]   = hb ? sval[e[j] + 1] : 0.f;
    cvB[j] = ((const uint4*)(h1t + (size_t)c1 * kN))[l];
  }
  int rem = 0;
#pragma unroll
  for (int j = 0; j < 4; ++j) {
    int d = e1[j] - e[j];
    rem = (d > rem) ? d : rem;
  }

#pragma unroll 1
  for (int k = 0; k < rem; k += 2) {
#pragma unroll
    for (int j = 0; j < 4; ++j) {        // FMA edge k, refill with edge k+2
      FMA8A(a[j], cvA[j], vA[j]);
      int m = e[j] + k + 2;
      bool h = m < e1[j];
      int c = h ? scol[m] : 0;
      vA[j] = h ? sval[m] : 0.f;
      cvA[j] = ((const uint4*)(h1t + (size_t)c * kN))[l];
    }
#pragma unroll
    for (int j = 0; j < 4; ++j) {        // FMA edge k+1, refill with edge k+3
      FMA8A(a[j], cvB[j], vB[j]);
      int m = e[j] + k + 3;
      bool h = m < e1[j];
      int c = h ? scol[m] : 0;
      vB[j] = h ? sval[m] : 0.f;
      cvB[j] = ((const uint4*)(h1t + (size_t)c * kN))[l];
    }
  }

  // LDS transpose tile + coalesced write
#pragma unroll
  for (int j = 0; j < 4; ++j) {
    int rl = w * 4 + j;
    int sw = (rl & 7) << 2;
    *(float4*)&tile[rl * 512 + ((8 * l) ^ sw)]     = make_float4(a[j][0], a[j][1], a[j][2], a[j][3]);
    *(float4*)&tile[rl * 512 + ((8 * l + 4) ^ sw)] = make_float4(a[j][4], a[j][5], a[j][6], a[j][7]);
  }
  __syncthreads();
  int r = l & 31;
  int swr = (r & 7) << 2;
#pragma unroll
  for (int it = 0; it < 32; ++it) {
    int n = it * 16 + w * 2 + (l >> 5);
    out[(size_t)n * kC + r0 + r] = tile[r * 512 + (n ^ swr)];
  }
}

extern "C" void kernel_launch(void* const* d_in, const int* in_sizes, int n_in,
                              void* d_out, int out_size, void* d_ws, size_t ws_size,
                              hipStream_t stream) {
  (void)in_sizes; (void)n_in; (void)out_size; (void)ws_size;
  const float* enc   = (const float*)d_in[0];
  const float* W     = (const float*)d_in[1];
  const float* bias  = (const float*)d_in[2];
  const float* Avals = (const float*)d_in[3];
  const int*   bidx  = (const int*)d_in[4];
  const int*   tgt   = (const int*)d_in[5];
  const int*   Arow  = (const int*)d_in[6];
  const int*   Acol  = Arow + kNNZ;
  float* out = (float*)d_out;

  char* ws = (char*)d_ws;
  float* mean   = (float*)(ws);                       //   4 KB
  float* rstd   = (float*)(ws + 4096);                //   4 KB
  u16*   Bp     = (u16*)  (ws + 8192);                //   1 MB fragment-major h0
  int*   rowptr = (int*)  (ws + 1056768);             // 256 KB (+1)
  int*   cursor = (int*)  (ws + 1319168);             // 256 KB
  int*   scol   = (int*)  (ws + 1581312);             //   1 MB
  float* sval   = (float*)(ws + 2629888);             //   1 MB
  float* part   = (float*)(ws + 3678464);             //  64 KB
  u16*   h1t    = (u16*)  (ws + 4194304);             //  64 MB

  hipMemsetAsync(rowptr, 0, (kC + 1) * sizeof(int), stream);
  k_bn_part<<<dim3(4, 8), 256, 0, stream>>>(enc, bidx, tgt, part);
  k_bn_fin<<<4, 256, 0, stream>>>(part, mean, rstd);
  k_bn_pack<<<256, 256, 0, stream>>>(enc, bidx, tgt, mean, rstd, Bp);
  k_hist<<<kNNZ / 256, 256, 0, stream>>>(Arow, rowptr);
  k_scan<<<1, 1024, 0, stream>>>(rowptr, cursor);
  k_scatter<<<kNNZ / 256, 256, 0, stream>>>(Arow, Acol, Avals, cursor, scol, sval);
  k_gemm_f5<<<kC / 64, 512, 0, stream>>>(W, Bp, bias, h1t);
  k_spmm<<<kC / 32, 512, 0, stream>>>(h1t, rowptr, scol, sval, out);
}